// Round 1
// baseline (11793.269 us; speedup 1.0000x reference)
//
#include <hip/hip_runtime.h>

#define EPS 1e-12f

constexpr int H = 768, W = 768, C = 3;
constexpr int HW = H * W;
constexpr int CHW = C * HW;
constexpr int TS = 32;            // output tile
constexpr int HALO = 7;           // 15x15 kernel
constexpr int PT = TS + 2 * HALO; // 46
constexpr int LDST = 48;          // padded LDS stride (16B-aligned rows)
constexpr int RHALO = 2;          // 5x5 kernel
constexpr int PR = TS + 2 * RHALO; // 36
constexpr int LDSR = 40;

__device__ __forceinline__ float block_reduce_256(float v, float* redbuf) {
    #pragma unroll
    for (int off = 32; off > 0; off >>= 1) v += __shfl_down(v, off, 64);
    const int tid = threadIdx.x;
    if ((tid & 63) == 0) redbuf[tid >> 6] = v;
    __syncthreads();
    return redbuf[0] + redbuf[1] + redbuf[2] + redbuf[3];
}

// MODE 0: prologue  (in = image; t0 = image - corr15(image); no p write, no beta)
// MODE 1: iter 0    (in = p0;    t0 = corr15(p0);            no p write, no beta)
// MODE 2: iter >= 1 (pe = r + beta*pin computed on the fly incl. halo; t0 = corr15(pe); pe -> pout)
template <int MODE>
__global__ __launch_bounds__(256) void stage1_k(
    const float* __restrict__ in, const float* __restrict__ rvec,
    const float* __restrict__ k15, const float* __restrict__ rks,
    float* __restrict__ t0, float* __restrict__ t1, float* __restrict__ t2,
    float* __restrict__ pout,
    const float* __restrict__ bnum, const float* __restrict__ bden)
{
    __shared__ float sp[PT * LDST];
    const int c = blockIdx.z;
    const int bx = blockIdx.x * TS, by = blockIdx.y * TS;
    const int tid = threadIdx.x;
    const float* inC = in + c * HW;
    float beta = 0.f;
    if (MODE == 2) beta = bnum[c] / (bden[c] + EPS);

    for (int t = tid; t < PT * PT; t += 256) {
        const int ly = t / PT, lx = t - ly * PT;
        const int gy = by - HALO + ly, gx = bx - HALO + lx;
        float v = 0.f;
        if ((unsigned)gy < (unsigned)H && (unsigned)gx < (unsigned)W) {
            const int g = gy * W + gx;
            v = inC[g];
            if (MODE == 2) v = rvec[c * HW + g] + beta * v;
        }
        sp[ly * LDST + lx] = v;
    }
    __syncthreads();

    const int oy = tid >> 3;
    const int ox = (tid & 7) << 2;

    // 15x15 correlation
    float a0 = 0, a1 = 0, a2 = 0, a3 = 0;
    #pragma unroll 1
    for (int i = 0; i < 15; ++i) {
        const float* rowp = sp + (oy + i) * LDST + ox;
        float seg[20];
        *(float4*)(seg + 0)  = *(const float4*)(rowp + 0);
        *(float4*)(seg + 4)  = *(const float4*)(rowp + 4);
        *(float4*)(seg + 8)  = *(const float4*)(rowp + 8);
        *(float4*)(seg + 12) = *(const float4*)(rowp + 12);
        *(float4*)(seg + 16) = *(const float4*)(rowp + 16);
        const float* kr = k15 + i * 15;
        #pragma unroll
        for (int j = 0; j < 15; ++j) {
            const float kv = kr[j];
            a0 = fmaf(seg[j + 0], kv, a0);
            a1 = fmaf(seg[j + 1], kv, a1);
            a2 = fmaf(seg[j + 2], kv, a2);
            a3 = fmaf(seg[j + 3], kv, a3);
        }
    }

    // two 5x5 correlations (same LDS tile, window offset HALO-RHALO = 5)
    float b0 = 0, b1 = 0, b2 = 0, b3 = 0;
    float c0 = 0, c1 = 0, c2 = 0, c3 = 0;
    #pragma unroll 1
    for (int i = 0; i < 5; ++i) {
        const float* rowp = sp + (oy + 5 + i) * LDST + ox + 4;
        float seg[12];
        *(float4*)(seg + 0) = *(const float4*)(rowp + 0);
        *(float4*)(seg + 4) = *(const float4*)(rowp + 4);
        *(float4*)(seg + 8) = *(const float4*)(rowp + 8);
        const float* r0k = rks + i * 5;
        const float* r1k = rks + 25 + i * 5;
        #pragma unroll
        for (int j = 0; j < 5; ++j) {
            const float k0 = r0k[j], k1 = r1k[j];
            b0 = fmaf(seg[j + 1], k0, b0);
            b1 = fmaf(seg[j + 2], k0, b1);
            b2 = fmaf(seg[j + 3], k0, b2);
            b3 = fmaf(seg[j + 4], k0, b3);
            c0 = fmaf(seg[j + 1], k1, c0);
            c1 = fmaf(seg[j + 2], k1, c1);
            c2 = fmaf(seg[j + 3], k1, c2);
            c3 = fmaf(seg[j + 4], k1, c3);
        }
    }

    const int g = c * HW + (by + oy) * W + bx + ox;
    float4 o0;
    if (MODE == 0) {
        const float* ctr = sp + (oy + HALO) * LDST + ox + HALO;
        o0 = make_float4(ctr[0] - a0, ctr[1] - a1, ctr[2] - a2, ctr[3] - a3);
    } else {
        o0 = make_float4(a0, a1, a2, a3);
    }
    *(float4*)(t0 + g) = o0;
    *(float4*)(t1 + g) = make_float4(b0, b1, b2, b3);
    *(float4*)(t2 + g) = make_float4(c0, c1, c2, c3);
    if (MODE == 2) {
        const float* ctr = sp + (oy + HALO) * LDST + ox + HALO;
        *(float4*)(pout + g) = make_float4(ctr[0], ctr[1], ctr[2], ctr[3]);
    }
}

// MODE 0: prologue: r0 = corrT(t0,k) - w0^2*corrT(t1,rk0) - w1^2*corrT(t2,rk1)
//         writes r0 -> outR, r0 -> outP0, image -> outX; accumulates sum(r0^2) into red[c]
// MODE 1: Ap = corrT(t0,k) + w0^2*corrT(t1,rk0) + w1^2*corrT(t2,rk1)
//         writes Ap; accumulates sum(p*Ap) into red[c]
template <int MODE>
__global__ __launch_bounds__(256) void stage2_k(
    const float* __restrict__ t0, const float* __restrict__ t1, const float* __restrict__ t2,
    const float* __restrict__ k15, const float* __restrict__ rks,
    const float* __restrict__ rw,
    const float* __restrict__ img, const float* __restrict__ p,
    float* __restrict__ Ap, float* __restrict__ outR, float* __restrict__ outP0,
    float* __restrict__ outX, float* __restrict__ red)
{
    __shared__ float s0[PT * LDST];
    __shared__ float s1[PR * LDSR];
    __shared__ float s2[PR * LDSR];
    __shared__ float redbuf[4];
    const int c = blockIdx.z;
    const int bx = blockIdx.x * TS, by = blockIdx.y * TS;
    const int tid = threadIdx.x;
    const float* t0C = t0 + c * HW;
    const float* t1C = t1 + c * HW;
    const float* t2C = t2 + c * HW;

    for (int t = tid; t < PT * PT; t += 256) {
        const int ly = t / PT, lx = t - ly * PT;
        const int gy = by - HALO + ly, gx = bx - HALO + lx;
        s0[ly * LDST + lx] =
            ((unsigned)gy < (unsigned)H && (unsigned)gx < (unsigned)W) ? t0C[gy * W + gx] : 0.f;
    }
    for (int t = tid; t < PR * PR; t += 256) {
        const int ly = t / PR, lx = t - ly * PR;
        const int gy = by - RHALO + ly, gx = bx - RHALO + lx;
        float v1 = 0.f, v2 = 0.f;
        if ((unsigned)gy < (unsigned)H && (unsigned)gx < (unsigned)W) {
            const int g = gy * W + gx;
            v1 = t1C[g]; v2 = t2C[g];
        }
        s1[ly * LDSR + lx] = v1;
        s2[ly * LDSR + lx] = v2;
    }
    __syncthreads();

    const int oy = tid >> 3;
    const int ox = (tid & 7) << 2;

    // corrT with 15x15 (flipped kernel)
    float a0 = 0, a1 = 0, a2 = 0, a3 = 0;
    #pragma unroll 1
    for (int i = 0; i < 15; ++i) {
        const float* rowp = s0 + (oy + i) * LDST + ox;
        float seg[20];
        *(float4*)(seg + 0)  = *(const float4*)(rowp + 0);
        *(float4*)(seg + 4)  = *(const float4*)(rowp + 4);
        *(float4*)(seg + 8)  = *(const float4*)(rowp + 8);
        *(float4*)(seg + 12) = *(const float4*)(rowp + 12);
        *(float4*)(seg + 16) = *(const float4*)(rowp + 16);
        const float* kr = k15 + (14 - i) * 15;
        #pragma unroll
        for (int j = 0; j < 15; ++j) {
            const float kv = kr[14 - j];
            a0 = fmaf(seg[j + 0], kv, a0);
            a1 = fmaf(seg[j + 1], kv, a1);
            a2 = fmaf(seg[j + 2], kv, a2);
            a3 = fmaf(seg[j + 3], kv, a3);
        }
    }

    // corrT with the two 5x5 (flipped)
    float b0 = 0, b1 = 0, b2 = 0, b3 = 0;
    float c0 = 0, c1 = 0, c2 = 0, c3 = 0;
    #pragma unroll 1
    for (int i = 0; i < 5; ++i) {
        const float* r1p = s1 + (oy + i) * LDSR + ox;
        const float* r2p = s2 + (oy + i) * LDSR + ox;
        float sA[12], sB[12];
        *(float4*)(sA + 0) = *(const float4*)(r1p + 0);
        *(float4*)(sA + 4) = *(const float4*)(r1p + 4);
        *(float4*)(sA + 8) = *(const float4*)(r1p + 8);
        *(float4*)(sB + 0) = *(const float4*)(r2p + 0);
        *(float4*)(sB + 4) = *(const float4*)(r2p + 4);
        *(float4*)(sB + 8) = *(const float4*)(r2p + 8);
        const float* r0k = rks + (4 - i) * 5;
        const float* r1k = rks + 25 + (4 - i) * 5;
        #pragma unroll
        for (int j = 0; j < 5; ++j) {
            const float k0 = r0k[4 - j], k1 = r1k[4 - j];
            b0 = fmaf(sA[j + 0], k0, b0);
            b1 = fmaf(sA[j + 1], k0, b1);
            b2 = fmaf(sA[j + 2], k0, b2);
            b3 = fmaf(sA[j + 3], k0, b3);
            c0 = fmaf(sB[j + 0], k1, c0);
            c1 = fmaf(sB[j + 1], k1, c1);
            c2 = fmaf(sB[j + 2], k1, c2);
            c3 = fmaf(sB[j + 3], k1, c3);
        }
    }

    const float w0 = rw[0], w1 = rw[1];
    const float sgn = (MODE == 0) ? -1.f : 1.f;
    const float w02 = w0 * w0 * sgn, w12 = w1 * w1 * sgn;
    const float v0 = a0 + w02 * b0 + w12 * c0;
    const float v1 = a1 + w02 * b1 + w12 * c1;
    const float v2 = a2 + w02 * b2 + w12 * c2;
    const float v3 = a3 + w02 * b3 + w12 * c3;

    const int g = c * HW + (by + oy) * W + bx + ox;
    float local;
    if (MODE == 0) {
        const float4 v4 = make_float4(v0, v1, v2, v3);
        *(float4*)(outR + g) = v4;
        *(float4*)(outP0 + g) = v4;
        *(float4*)(outX + g) = *(const float4*)(img + g);
        local = v0 * v0 + v1 * v1 + v2 * v2 + v3 * v3;
    } else {
        *(float4*)(Ap + g) = make_float4(v0, v1, v2, v3);
        const float4 pv = *(const float4*)(p + g);
        local = pv.x * v0 + pv.y * v1 + pv.z * v2 + pv.w * v3;
    }
    const float tot = block_reduce_256(local, redbuf);
    if (tid == 0) atomicAdd(red + c, tot);
}

// x += alpha*p; r -= alpha*Ap; accumulate sum(r_new^2)
__global__ __launch_bounds__(256) void cg_update_k(
    float* __restrict__ x, float* __restrict__ r,
    const float* __restrict__ Ap, const float* __restrict__ p,
    const float* __restrict__ rtr_cur, const float* __restrict__ ptap,
    float* __restrict__ rtr_next)
{
    __shared__ float redbuf[4];
    const int c = blockIdx.z;
    const float alpha = rtr_cur[c] / (ptap[c] + EPS);
    const int idx = c * HW + (blockIdx.x * 256 + threadIdx.x) * 4;
    float4 xv = *(float4*)(x + idx);
    float4 rv = *(float4*)(r + idx);
    const float4 pv = *(const float4*)(p + idx);
    const float4 av = *(const float4*)(Ap + idx);
    xv.x = fmaf(alpha, pv.x, xv.x); rv.x = fmaf(-alpha, av.x, rv.x);
    xv.y = fmaf(alpha, pv.y, xv.y); rv.y = fmaf(-alpha, av.y, rv.y);
    xv.z = fmaf(alpha, pv.z, xv.z); rv.z = fmaf(-alpha, av.z, rv.z);
    xv.w = fmaf(alpha, pv.w, xv.w); rv.w = fmaf(-alpha, av.w, rv.w);
    *(float4*)(x + idx) = xv;
    *(float4*)(r + idx) = rv;
    const float local = rv.x * rv.x + rv.y * rv.y + rv.z * rv.z + rv.w * rv.w;
    const float tot = block_reduce_256(local, redbuf);
    if (threadIdx.x == 0) atomicAdd(rtr_next + c, tot);
}

// final: p = r + beta*p99
__global__ __launch_bounds__(256) void p_final_k(
    const float* __restrict__ r, const float* __restrict__ p99, float* __restrict__ pout,
    const float* __restrict__ num, const float* __restrict__ den)
{
    const int c = blockIdx.z;
    const float beta = num[c] / (den[c] + EPS);
    const int idx = c * HW + (blockIdx.x * 256 + threadIdx.x) * 4;
    const float4 rv = *(const float4*)(r + idx);
    const float4 pv = *(const float4*)(p99 + idx);
    *(float4*)(pout + idx) = make_float4(
        fmaf(beta, pv.x, rv.x), fmaf(beta, pv.y, rv.y),
        fmaf(beta, pv.z, rv.z), fmaf(beta, pv.w, rv.w));
}

extern "C" void kernel_launch(void* const* d_in, const int* in_sizes, int n_in,
                              void* d_out, int out_size, void* d_ws, size_t ws_size,
                              hipStream_t stream)
{
    const float* img = (const float*)d_in[0];
    const float* k15 = (const float*)d_in[1];
    const float* rks = (const float*)d_in[2];
    const float* rw  = (const float*)d_in[3];

    float* out = (float*)d_out;
    float* xs = out;            // x slot
    float* rs = out + CHW;      // r slot
    float* ps = out + 2 * CHW;  // p slot (also used as p double-buffer "buf1")

    float* ws   = (float*)d_ws;
    float* buf0 = ws;               // p buffer (even i)
    float* t0   = buf0 + CHW;
    float* t1   = t0 + CHW;
    float* t2   = t1 + CHW;
    float* Ap   = t2 + CHW;
    float* scal = Ap + CHW;         // rtr2[101][3] then ptap[100][3]
    float* rtr2 = scal;
    float* ptap = scal + 101 * 3;

    hipMemsetAsync(scal, 0, (101 * 3 + 100 * 3) * sizeof(float), stream);

    const dim3 gc(W / TS, H / TS, C), bc(256);
    const dim3 ge(HW / 1024, 1, C);

    // prologue: r0 = K^T b - A(x0), p0 = r0, x = image, rtr2[0] = ||r0||^2
    stage1_k<0><<<gc, bc, 0, stream>>>(img, nullptr, k15, rks, t0, t1, t2,
                                       nullptr, nullptr, nullptr);
    stage2_k<0><<<gc, bc, 0, stream>>>(t0, t1, t2, k15, rks, rw, img, nullptr,
                                       nullptr, rs, buf0, xs, rtr2);

    for (int i = 0; i < 100; ++i) {
        float* pin  = (i & 1) ? buf0 : ps;   // p_{i-1} lives in buf[(i-1)%2]
        float* pcur = (i & 1) ? ps : buf0;   // p_i lives in buf[i%2]
        if (i == 0) {
            stage1_k<1><<<gc, bc, 0, stream>>>(buf0, nullptr, k15, rks, t0, t1, t2,
                                               nullptr, nullptr, nullptr);
        } else {
            stage1_k<2><<<gc, bc, 0, stream>>>(pin, rs, k15, rks, t0, t1, t2,
                                               pcur, rtr2 + i * 3, rtr2 + (i - 1) * 3);
        }
        stage2_k<1><<<gc, bc, 0, stream>>>(t0, t1, t2, k15, rks, rw, nullptr, pcur,
                                           Ap, nullptr, nullptr, nullptr, ptap + i * 3);
        cg_update_k<<<ge, bc, 0, stream>>>(xs, rs, Ap, pcur,
                                           rtr2 + i * 3, ptap + i * 3, rtr2 + (i + 1) * 3);
    }
    // p_100 = r + beta_99 * p_99 ; p_99 is in buf[99%2] = ps (in-place elementwise is safe)
    p_final_k<<<ge, bc, 0, stream>>>(rs, ps, ps, rtr2 + 100 * 3, rtr2 + 99 * 3);
}

// Round 3
// 8086.109 us; speedup vs baseline: 1.4585x; 1.4585x over previous
//
#include <hip/hip_runtime.h>

#define EPS 1e-12f

constexpr int H = 768, W = 768, C = 3;
constexpr int HW = H * W;
constexpr int CHW = C * HW;

constexpr int TSX = 64, TSY = 32;      // output tile (8 px/thread, 256 threads)
constexpr int PTX = TSX + 14;          // 78 (halo 7)
constexpr int PTY = TSY + 14;          // 46
constexpr int LDS1 = 84;               // padded stride: 16B-aligned, all bank groups
constexpr int PRX = TSX + 4;           // 68 (halo 2)
constexpr int PRY = TSY + 4;           // 36
constexpr int LDS2 = 76;               // 16B-aligned, all bank groups

constexpr int NSLOT = 16;              // hashed atomic slots per scalar
constexpr int SSTR = 16;               // slot spacing in floats (64B -> own cacheline)
constexpr int SCALSZ = NSLOT * SSTR;   // floats per scalar-point

__device__ __forceinline__ float block_reduce_256(float v, float* redbuf) {
    #pragma unroll
    for (int off = 32; off > 0; off >>= 1) v += __shfl_down(v, off, 64);
    const int tid = threadIdx.x;
    if ((tid & 63) == 0) redbuf[tid >> 6] = v;
    __syncthreads();
    return redbuf[0] + redbuf[1] + redbuf[2] + redbuf[3];
}

__device__ __forceinline__ float sum_slots(const float* base, int c) {
    float s = 0.f;
    #pragma unroll
    for (int k = 0; k < NSLOT; ++k) s += base[k * SSTR + c];
    return s;
}

// MODE 0: prologue  (in = image; t0 = image - corr15(image))
// MODE 1: iter 0    (in = p0;    t0 = corr15(p0))
// MODE 2: iter >= 1 (pe = r + beta*pin on the fly incl. halo; t0 = corr15(pe); pe -> pout)
template <int MODE>
__global__ __launch_bounds__(256) void stage1_k(
    const float* __restrict__ in, const float* __restrict__ rvec,
    const float* __restrict__ k15, const float* __restrict__ rks,
    float* __restrict__ t0, float* __restrict__ t1, float* __restrict__ t2,
    float* __restrict__ pout,
    const float* __restrict__ bnum, const float* __restrict__ bden)
{
    __shared__ float sp[PTY * LDS1];
    __shared__ __align__(16) float kt[15 * 16];
    __shared__ __align__(16) float rkt[2 * 5 * 8];
    const int c = blockIdx.z;
    const int bx = blockIdx.x * TSX, by = blockIdx.y * TSY;
    const int tid = threadIdx.x;
    const float* inC = in + c * HW;

    float beta = 0.f;
    if (MODE == 2) {
        const float n = sum_slots(bnum, c), d = sum_slots(bden, c);
        beta = n / (d + EPS);
    }

    // stage taps (padded rows, 16B aligned)
    if (tid < 240) { const int i = tid >> 4, j = tid & 15; kt[tid] = (j < 15) ? k15[i * 15 + j] : 0.f; }
    if (tid < 80) {
        const int kk = tid / 40, rem = tid % 40, i = rem >> 3, j = rem & 7;
        rkt[tid] = (j < 5) ? rks[kk * 25 + i * 5 + j] : 0.f;
    }

    // stage data tile + halo
    for (int t = tid; t < PTY * PTX; t += 256) {
        const int ly = t / PTX, lx = t - ly * PTX;
        const int gy = by - 7 + ly, gx = bx - 7 + lx;
        float v = 0.f;
        if ((unsigned)gy < (unsigned)H && (unsigned)gx < (unsigned)W) {
            const int g = gy * W + gx;
            v = inC[g];
            if (MODE == 2) v = rvec[c * HW + g] + beta * v;
        }
        sp[ly * LDS1 + lx] = v;
    }
    __syncthreads();

    const int oy = tid >> 3;
    const int ox = (tid & 7) << 3;

    // 15x15 correlation, 8 px/thread
    float acc[8];
    #pragma unroll
    for (int k = 0; k < 8; ++k) acc[k] = 0.f;
    #pragma unroll 1
    for (int i = 0; i < 15; ++i) {
        const float* rowp = sp + (oy + i) * LDS1 + ox;
        float seg[24];
        #pragma unroll
        for (int q = 0; q < 6; ++q) *(float4*)(seg + 4 * q) = *(const float4*)(rowp + 4 * q);
        float kv[16];
        #pragma unroll
        for (int q = 0; q < 4; ++q) *(float4*)(kv + 4 * q) = *(const float4*)(kt + i * 16 + 4 * q);
        #pragma unroll
        for (int j = 0; j < 15; ++j)
            #pragma unroll
            for (int k = 0; k < 8; ++k) acc[k] = fmaf(seg[j + k], kv[j], acc[k]);
    }

    // two 5x5 correlations (window offset 5 in the same tile)
    float accB[8], accC[8];
    #pragma unroll
    for (int k = 0; k < 8; ++k) { accB[k] = 0.f; accC[k] = 0.f; }
    #pragma unroll 1
    for (int i = 0; i < 5; ++i) {
        const float* rowp = sp + (oy + 5 + i) * LDS1 + ox + 4;
        float seg[16];
        #pragma unroll
        for (int q = 0; q < 4; ++q) *(float4*)(seg + 4 * q) = *(const float4*)(rowp + 4 * q);
        float kb[8], kc[8];
        *(float4*)(kb) = *(const float4*)(rkt + i * 8);
        *(float4*)(kb + 4) = *(const float4*)(rkt + i * 8 + 4);
        *(float4*)(kc) = *(const float4*)(rkt + 40 + i * 8);
        *(float4*)(kc + 4) = *(const float4*)(rkt + 40 + i * 8 + 4);
        #pragma unroll
        for (int j = 0; j < 5; ++j)
            #pragma unroll
            for (int k = 0; k < 8; ++k) {
                accB[k] = fmaf(seg[1 + k + j], kb[j], accB[k]);
                accC[k] = fmaf(seg[1 + k + j], kc[j], accC[k]);
            }
    }

    const int g = c * HW + (by + oy) * W + bx + ox;
    const float* ctr = sp + (oy + 7) * LDS1 + ox + 7;
    if (MODE == 0) {
        #pragma unroll
        for (int k = 0; k < 8; ++k) acc[k] = ctr[k] - acc[k];
    }
    *(float4*)(t0 + g)     = make_float4(acc[0], acc[1], acc[2], acc[3]);
    *(float4*)(t0 + g + 4) = make_float4(acc[4], acc[5], acc[6], acc[7]);
    *(float4*)(t1 + g)     = make_float4(accB[0], accB[1], accB[2], accB[3]);
    *(float4*)(t1 + g + 4) = make_float4(accB[4], accB[5], accB[6], accB[7]);
    *(float4*)(t2 + g)     = make_float4(accC[0], accC[1], accC[2], accC[3]);
    *(float4*)(t2 + g + 4) = make_float4(accC[4], accC[5], accC[6], accC[7]);
    if (MODE == 2) {
        *(float4*)(pout + g)     = make_float4(ctr[0], ctr[1], ctr[2], ctr[3]);
        *(float4*)(pout + g + 4) = make_float4(ctr[4], ctr[5], ctr[6], ctr[7]);
    }
}

// MODE 0: r0 = corrT(t0) - w^2 terms; writes r0->outR, r0->outP0, img->outX; red += ||r0||^2
// MODE 1: Ap = corrT(t0) + w^2 terms; writes Ap; red += p.Ap
template <int MODE>
__global__ __launch_bounds__(256) void stage2_k(
    const float* __restrict__ t0, const float* __restrict__ t1, const float* __restrict__ t2,
    const float* __restrict__ k15, const float* __restrict__ rks,
    const float* __restrict__ rw,
    const float* __restrict__ img, const float* __restrict__ p,
    float* __restrict__ Ap, float* __restrict__ outR, float* __restrict__ outP0,
    float* __restrict__ outX, float* __restrict__ red)
{
    __shared__ float s0[PTY * LDS1];
    __shared__ float s1[PRY * LDS2];
    __shared__ float s2[PRY * LDS2];
    __shared__ __align__(16) float kt[15 * 16];
    __shared__ __align__(16) float rkt[2 * 5 * 8];
    __shared__ float redbuf[4];
    const int c = blockIdx.z;
    const int bx = blockIdx.x * TSX, by = blockIdx.y * TSY;
    const int tid = threadIdx.x;
    const float* t0C = t0 + c * HW;
    const float* t1C = t1 + c * HW;
    const float* t2C = t2 + c * HW;

    // stage FLIPPED taps so the hot loop is identical to stage1
    if (tid < 240) { const int i = tid >> 4, j = tid & 15; kt[tid] = (j < 15) ? k15[(14 - i) * 15 + (14 - j)] : 0.f; }
    if (tid < 80) {
        const int kk = tid / 40, rem = tid % 40, i = rem >> 3, j = rem & 7;
        rkt[tid] = (j < 5) ? rks[kk * 25 + (4 - i) * 5 + (4 - j)] : 0.f;
    }

    for (int t = tid; t < PTY * PTX; t += 256) {
        const int ly = t / PTX, lx = t - ly * PTX;
        const int gy = by - 7 + ly, gx = bx - 7 + lx;
        s0[ly * LDS1 + lx] =
            ((unsigned)gy < (unsigned)H && (unsigned)gx < (unsigned)W) ? t0C[gy * W + gx] : 0.f;
    }
    for (int t = tid; t < PRY * PRX; t += 256) {
        const int ly = t / PRX, lx = t - ly * PRX;
        const int gy = by - 2 + ly, gx = bx - 2 + lx;
        float v1 = 0.f, v2 = 0.f;
        if ((unsigned)gy < (unsigned)H && (unsigned)gx < (unsigned)W) {
            const int g = gy * W + gx;
            v1 = t1C[g]; v2 = t2C[g];
        }
        s1[ly * LDS2 + lx] = v1;
        s2[ly * LDS2 + lx] = v2;
    }
    __syncthreads();

    const int oy = tid >> 3;
    const int ox = (tid & 7) << 3;

    float acc[8];
    #pragma unroll
    for (int k = 0; k < 8; ++k) acc[k] = 0.f;
    #pragma unroll 1
    for (int i = 0; i < 15; ++i) {
        const float* rowp = s0 + (oy + i) * LDS1 + ox;
        float seg[24];
        #pragma unroll
        for (int q = 0; q < 6; ++q) *(float4*)(seg + 4 * q) = *(const float4*)(rowp + 4 * q);
        float kv[16];
        #pragma unroll
        for (int q = 0; q < 4; ++q) *(float4*)(kv + 4 * q) = *(const float4*)(kt + i * 16 + 4 * q);
        #pragma unroll
        for (int j = 0; j < 15; ++j)
            #pragma unroll
            for (int k = 0; k < 8; ++k) acc[k] = fmaf(seg[j + k], kv[j], acc[k]);
    }

    float accB[8], accC[8];
    #pragma unroll
    for (int k = 0; k < 8; ++k) { accB[k] = 0.f; accC[k] = 0.f; }
    #pragma unroll 1
    for (int i = 0; i < 5; ++i) {
        const float* r1p = s1 + (oy + i) * LDS2 + ox;
        const float* r2p = s2 + (oy + i) * LDS2 + ox;
        float sA[12], sB[12];
        #pragma unroll
        for (int q = 0; q < 3; ++q) *(float4*)(sA + 4 * q) = *(const float4*)(r1p + 4 * q);
        #pragma unroll
        for (int q = 0; q < 3; ++q) *(float4*)(sB + 4 * q) = *(const float4*)(r2p + 4 * q);
        float kb[8], kc[8];
        *(float4*)(kb) = *(const float4*)(rkt + i * 8);
        *(float4*)(kb + 4) = *(const float4*)(rkt + i * 8 + 4);
        *(float4*)(kc) = *(const float4*)(rkt + 40 + i * 8);
        *(float4*)(kc + 4) = *(const float4*)(rkt + 40 + i * 8 + 4);
        #pragma unroll
        for (int j = 0; j < 5; ++j)
            #pragma unroll
            for (int k = 0; k < 8; ++k) {
                accB[k] = fmaf(sA[k + j], kb[j], accB[k]);
                accC[k] = fmaf(sB[k + j], kc[j], accC[k]);
            }
    }

    const float w0 = rw[0], w1 = rw[1];
    const float sgn = (MODE == 0) ? -1.f : 1.f;
    const float w02 = w0 * w0 * sgn, w12 = w1 * w1 * sgn;
    float v[8];
    #pragma unroll
    for (int k = 0; k < 8; ++k) v[k] = acc[k] + w02 * accB[k] + w12 * accC[k];

    const int g = c * HW + (by + oy) * W + bx + ox;
    float local = 0.f;
    if (MODE == 0) {
        *(float4*)(outR + g)      = make_float4(v[0], v[1], v[2], v[3]);
        *(float4*)(outR + g + 4)  = make_float4(v[4], v[5], v[6], v[7]);
        *(float4*)(outP0 + g)     = make_float4(v[0], v[1], v[2], v[3]);
        *(float4*)(outP0 + g + 4) = make_float4(v[4], v[5], v[6], v[7]);
        *(float4*)(outX + g)      = *(const float4*)(img + g);
        *(float4*)(outX + g + 4)  = *(const float4*)(img + g + 4);
        #pragma unroll
        for (int k = 0; k < 8; ++k) local += v[k] * v[k];
    } else {
        *(float4*)(Ap + g)     = make_float4(v[0], v[1], v[2], v[3]);
        *(float4*)(Ap + g + 4) = make_float4(v[4], v[5], v[6], v[7]);
        const float4 p0 = *(const float4*)(p + g);
        const float4 p1 = *(const float4*)(p + g + 4);
        local = p0.x * v[0] + p0.y * v[1] + p0.z * v[2] + p0.w * v[3]
              + p1.x * v[4] + p1.y * v[5] + p1.z * v[6] + p1.w * v[7];
    }
    const float tot = block_reduce_256(local, redbuf);
    if (tid == 0) {
        const int bid = blockIdx.y * gridDim.x + blockIdx.x;
        atomicAdd(red + (bid & (NSLOT - 1)) * SSTR + c, tot);
    }
}

// x += alpha*p; r -= alpha*Ap; accumulate ||r_new||^2 (8 px/thread)
__global__ __launch_bounds__(256) void cg_update_k(
    float* __restrict__ x, float* __restrict__ r,
    const float* __restrict__ Ap, const float* __restrict__ p,
    const float* __restrict__ rtr_cur, const float* __restrict__ ptap,
    float* __restrict__ rtr_next)
{
    __shared__ float redbuf[4];
    const int c = blockIdx.z;
    const float n = sum_slots(rtr_cur, c), d = sum_slots(ptap, c);
    const float alpha = n / (d + EPS);
    const int idx = c * HW + (blockIdx.x * 256 + threadIdx.x) * 8;
    float local = 0.f;
    #pragma unroll
    for (int h = 0; h < 2; ++h) {
        const int o = idx + 4 * h;
        float4 xv = *(float4*)(x + o);
        float4 rv = *(float4*)(r + o);
        const float4 pv = *(const float4*)(p + o);
        const float4 av = *(const float4*)(Ap + o);
        xv.x = fmaf(alpha, pv.x, xv.x); rv.x = fmaf(-alpha, av.x, rv.x);
        xv.y = fmaf(alpha, pv.y, xv.y); rv.y = fmaf(-alpha, av.y, rv.y);
        xv.z = fmaf(alpha, pv.z, xv.z); rv.z = fmaf(-alpha, av.z, rv.z);
        xv.w = fmaf(alpha, pv.w, xv.w); rv.w = fmaf(-alpha, av.w, rv.w);
        *(float4*)(x + o) = xv;
        *(float4*)(r + o) = rv;
        local += rv.x * rv.x + rv.y * rv.y + rv.z * rv.z + rv.w * rv.w;
    }
    const float tot = block_reduce_256(local, redbuf);
    if (threadIdx.x == 0)
        atomicAdd(rtr_next + ((int)blockIdx.x & (NSLOT - 1)) * SSTR + c, tot);
}

// final: p = r + beta*p99
__global__ __launch_bounds__(256) void p_final_k(
    const float* __restrict__ r, const float* __restrict__ p99, float* __restrict__ pout,
    const float* __restrict__ num, const float* __restrict__ den)
{
    const int c = blockIdx.z;
    const float beta = sum_slots(num, c) / (sum_slots(den, c) + EPS);
    const int idx = c * HW + (blockIdx.x * 256 + threadIdx.x) * 8;
    #pragma unroll
    for (int h = 0; h < 2; ++h) {
        const int o = idx + 4 * h;
        const float4 rv = *(const float4*)(r + o);
        const float4 pv = *(const float4*)(p99 + o);
        *(float4*)(pout + o) = make_float4(
            fmaf(beta, pv.x, rv.x), fmaf(beta, pv.y, rv.y),
            fmaf(beta, pv.z, rv.z), fmaf(beta, pv.w, rv.w));
    }
}

extern "C" void kernel_launch(void* const* d_in, const int* in_sizes, int n_in,
                              void* d_out, int out_size, void* d_ws, size_t ws_size,
                              hipStream_t stream)
{
    const float* img = (const float*)d_in[0];
    const float* k15 = (const float*)d_in[1];
    const float* rks = (const float*)d_in[2];
    const float* rw  = (const float*)d_in[3];

    float* out = (float*)d_out;
    float* xs = out;            // x slot
    float* rs = out + CHW;      // r slot
    float* ps = out + 2 * CHW;  // p slot (doubles as odd-parity p buffer)

    float* ws   = (float*)d_ws;
    float* buf0 = ws;               // p buffer (even parity)
    float* t0   = buf0 + CHW;
    float* t1   = t0 + CHW;
    float* t2   = t1 + CHW;
    float* Ap   = t2 + CHW;
    float* scal = Ap + CHW;         // [101 rtr2][100 ptap] each SCALSZ floats
    float* rtr2 = scal;
    float* ptap = scal + 101 * SCALSZ;

    hipMemsetAsync(scal, 0, (size_t)(101 + 100) * SCALSZ * sizeof(float), stream);

    const dim3 gc(W / TSX, H / TSY, C), bc(256);
    const dim3 ge(HW / 2048, 1, C);

    // prologue
    stage1_k<0><<<gc, bc, 0, stream>>>(img, nullptr, k15, rks, t0, t1, t2,
                                       nullptr, nullptr, nullptr);
    stage2_k<0><<<gc, bc, 0, stream>>>(t0, t1, t2, k15, rks, rw, img, nullptr,
                                       nullptr, rs, buf0, xs, rtr2);

    for (int i = 0; i < 100; ++i) {
        float* pin  = (i & 1) ? buf0 : ps;
        float* pcur = (i & 1) ? ps : buf0;
        if (i == 0) {
            stage1_k<1><<<gc, bc, 0, stream>>>(buf0, nullptr, k15, rks, t0, t1, t2,
                                               nullptr, nullptr, nullptr);
        } else {
            stage1_k<2><<<gc, bc, 0, stream>>>(pin, rs, k15, rks, t0, t1, t2,
                                               pcur, rtr2 + i * SCALSZ, rtr2 + (i - 1) * SCALSZ);
        }
        stage2_k<1><<<gc, bc, 0, stream>>>(t0, t1, t2, k15, rks, rw, nullptr, pcur,
                                           Ap, nullptr, nullptr, nullptr, ptap + i * SCALSZ);
        cg_update_k<<<ge, bc, 0, stream>>>(xs, rs, Ap, pcur,
                                           rtr2 + i * SCALSZ, ptap + i * SCALSZ,
                                           rtr2 + (i + 1) * SCALSZ);
    }
    p_final_k<<<ge, bc, 0, stream>>>(rs, ps, ps, rtr2 + 100 * SCALSZ, rtr2 + 99 * SCALSZ);
}